// Round 2
// baseline (265.652 us; speedup 1.0000x reference)
//
#include <hip/hip_runtime.h>

#define TT 2048
#define BLOCK 256
#define WAVES (BLOCK / 64)   // 4 rows per block, one per wave

#define LOG2E 1.4426950408889634f

typedef float vf4 __attribute__((ext_vector_type(4)));

// nontemporal 16B store (global_store_dwordx4 ... nt)
__device__ __forceinline__ void nt_store4(float4* p, float x, float y, float z, float w) {
    vf4 v = {x, y, z, w};
    __builtin_nontemporal_store(v, (vf4*)p);
}

__device__ __forceinline__ float fast_sigmoid_e2(float u) {
    // caller passes u = -x * log2e ; returns 1/(1+2^u) = sigmoid(x)
    return __builtin_amdgcn_rcpf(1.0f + __builtin_amdgcn_exp2f(u));
}

__global__ __launch_bounds__(BLOCK) void score_branch_kernel(
    const float* __restrict__ logits, const int* __restrict__ seq_len,
    float* __restrict__ out)
{
    __shared__ float s_scores[TT];

    const int b    = blockIdx.y;
    const int row0 = blockIdx.x * WAVES;
    const int tid  = threadIdx.x;
    const int lane = tid & 63;
    const int wv   = tid >> 6;
    const int L    = seq_len[b];   // in [1, TT], block-uniform (SGPR)

    const int i = row0 + wv;       // this wave's row
    float4* orow4 = (float4*)(out + ((size_t)b * TT + (size_t)i) * TT);

    // ---- fully-invalid block: no staging, no barrier, just stream zeros ----
    if (row0 >= L) {
        #pragma unroll
        for (int q = 0; q < 8; ++q)
            nt_store4(&orow4[q * 64 + lane], 0.f, 0.f, 0.f, 0.f);
        return;
    }

    // ---- stage scores = sigmoid(logits[b,:]) into LDS (only j < L needed) ----
    const float4* lg4 = (const float4*)(logits + (size_t)b * TT);
    float4* s4 = (float4*)s_scores;
    #pragma unroll
    for (int k = 0; k < TT / (BLOCK * 4); ++k) {   // 2 iters
        int idx4 = tid + k * BLOCK;
        if (idx4 * 4 < L) {          // entries >= L are never consumed unmasked
            float4 v = lg4[idx4];
            float4 s;
            s.x = fast_sigmoid_e2(-LOG2E * v.x);
            s.y = fast_sigmoid_e2(-LOG2E * v.y);
            s.z = fast_sigmoid_e2(-LOG2E * v.z);
            s.w = fast_sigmoid_e2(-LOG2E * v.w);
            s4[idx4] = s;
        }
    }
    __syncthreads();   // the ONLY block barrier — waves free-run after this

    // ---- invalid row inside a mixed block: zeros (after barrier) ----
    if (i >= L) {
        #pragma unroll
        for (int q = 0; q < 8; ++q)
            nt_store4(&orow4[q * 64 + lane], 0.f, 0.f, 0.f, 0.f);
        return;
    }

    // ---- early zero stores for fully-masked column groups (wave-uniform) ----
    // Issue these BEFORE the exp chain so store traffic overlaps compute.
    #pragma unroll
    for (int q = 0; q < 8; ++q) {
        if (q * 256 >= L)
            nt_store4(&orow4[q * 64 + lane], 0.f, 0.f, 0.f, 0.f);
    }

    const float si = s_scores[i];

    // Each lane: up to 8 float4 groups, j4 = q*64 + lane (coalesced).
    // Group q is fully valid if (q+1)*256 <= L, partial if q*256 < L < (q+1)*256.
    float4 e4[8];
    float partial = 0.f;
    #pragma unroll
    for (int q = 0; q < 8; ++q) {
        if (q * 256 < L) {                       // uniform branch, static q
            const int idx4 = q * 64 + lane;
            float4 sj = s4[idx4];                // garbage beyond L is masked below
            const int j0 = idx4 * 4;
            const bool fullgrp = ((q + 1) * 256 <= L);
            float vals[4] = {sj.x, sj.y, sj.z, sj.w};
            float* ev = (float*)&e4[q];
            #pragma unroll
            for (int qq = 0; qq < 4; ++qq) {
                float d  = si - vals[qq];
                // t = (0.5-|d|)/0.1 ; u = -t*log2e folded into one fma
                float u  = fmaf(fabsf(d), 10.0f * LOG2E, -5.0f * LOG2E);
                float p  = fast_sigmoid_e2(u);             // rel in (0,1)
                float ee = __builtin_amdgcn_exp2f(p * LOG2E); // exp(p), <e: no max-sub
                if (!fullgrp)
                    ee = (j0 + qq < L) ? ee : 0.0f;        // masked cols -> exact 0
                ev[qq] = ee;
                partial += ee;
            }
        }
    }

    // wave-private butterfly reduction — no LDS, no barrier
    #pragma unroll
    for (int off = 32; off > 0; off >>= 1)
        partial += __shfl_xor(partial, off, 64);
    const float inv = __builtin_amdgcn_rcpf(partial);   // denom >= e^sig(5) > 2.6

    #pragma unroll
    for (int q = 0; q < 8; ++q) {
        if (q * 256 < L) {
            nt_store4(&orow4[q * 64 + lane],
                      e4[q].x * inv, e4[q].y * inv, e4[q].z * inv, e4[q].w * inv);
        }
    }
}

extern "C" void kernel_launch(void* const* d_in, const int* in_sizes, int n_in,
                              void* d_out, int out_size, void* d_ws, size_t ws_size,
                              hipStream_t stream) {
    const float* logits  = (const float*)d_in[0];   // [B, T, 1] fp32
    const int*   seq_len = (const int*)d_in[1];     // [B] int32
    float*       out     = (float*)d_out;           // [B, T, T] fp32

    const int B = in_sizes[1];                      // 16
    dim3 grid(TT / WAVES, B);                       // (512, 16) = 8192 blocks
    score_branch_kernel<<<grid, dim3(BLOCK), 0, stream>>>(logits, seq_len, out);
}